// Round 2
// baseline (11.970 us; speedup 1.0000x reference)
//
#include <hip/hip_runtime.h>
#include <hip/hip_bf16.h>

// PQC classifier: circuit output is independent of the batch input x.
// Analytic reduction:
//   <Z0> = cos(theta_rx), <Z1> = cos(theta_ry), <Z2> = <Z3> = 1
//   logits = (cos tx + cos ty, 2); out = log_softmax(logits) broadcast to (bsz, 2).
// Kernel = compute 2 uniform scalars, broadcast-store 8 MB.
//
// Fast-math intrinsics (__cosf/__expf/__logf -> v_cos/v_exp/v_log_f32):
// error ~1e-6, threshold 1.58e-2. Grid-stride with 512 blocks so the
// uniform scalar preamble is paid by 2048 waves instead of 8192.

__global__ void __launch_bounds__(256) pqc_broadcast_kernel(
        const float* __restrict__ theta_rx,
        const float* __restrict__ theta_ry,
        float* __restrict__ out,
        int n4) {
    float cx = __cosf(theta_rx[0]);
    float cy = __cosf(theta_ry[0]);
    // logits l0 = cx+cy, l1 = 2.  d = l0 - 2 in [-4, 0].
    // o1 = -log(1 + e^d);  o0 = d + o1.
    float d  = cx + cy - 2.0f;
    float o1 = -__logf(1.0f + __expf(d));
    float o0 = d + o1;

    float4 v = make_float4(o0, o1, o0, o1);
    float4* o4 = reinterpret_cast<float4*>(out);

    int stride = gridDim.x * blockDim.x;
    for (int i = blockIdx.x * blockDim.x + threadIdx.x; i < n4; i += stride) {
        o4[i] = v;
    }
}

extern "C" void kernel_launch(void* const* d_in, const int* in_sizes, int n_in,
                              void* d_out, int out_size, void* d_ws, size_t ws_size,
                              hipStream_t stream) {
    // Inputs (setup_inputs order): x (bsz*16 f32), theta_rx (1), theta_ry (1), theta_rz (1).
    const float* theta_rx = (const float*)d_in[1];
    const float* theta_ry = (const float*)d_in[2];
    float* out = (float*)d_out;

    int n4 = out_size / 4;      // float4 chunks (out_size = 2^21 floats)
    int block = 256;
    int grid = 512;             // 4 float4 stores per thread, 8 waves/CU
    pqc_broadcast_kernel<<<grid, block, 0, stream>>>(theta_rx, theta_ry, out, n4);
}

// Round 3
// 10.141 us; speedup vs baseline: 1.1804x; 1.1804x over previous
//
#include <hip/hip_runtime.h>
#include <hip/hip_bf16.h>

// PQC classifier: circuit output is independent of the batch input x.
// Analytic reduction:
//   <Z0> = cos(theta_rx), <Z1> = cos(theta_ry), <Z2> = <Z3> = 1
//   logits = (cos tx + cos ty, 2); out = log_softmax(logits) broadcast to (bsz, 2).
// Kernel = compute 2 uniform scalars, broadcast-store 8 MB.
//
// Round-0 grid shape (one float4/thread, 2048 blocks) was fastest (10.1 us);
// grid-stride 512 blocks regressed (12.0 us). Keep fast-math intrinsics to
// minimize the load->compute->store dependency chain per wave.

__global__ void __launch_bounds__(256) pqc_broadcast_kernel(
        const float* __restrict__ theta_rx,
        const float* __restrict__ theta_ry,
        float* __restrict__ out,
        int n4) {
    float cx = __cosf(theta_rx[0]);
    float cy = __cosf(theta_ry[0]);
    // logits l0 = cx+cy, l1 = 2.  d = l0 - 2 in [-4, 0].
    // o1 = -log(1 + e^d);  o0 = d + o1.
    float d  = cx + cy - 2.0f;
    float o1 = -__logf(1.0f + __expf(d));
    float o0 = d + o1;

    float4 v = make_float4(o0, o1, o0, o1);
    int i = blockIdx.x * blockDim.x + threadIdx.x;
    if (i < n4) {
        reinterpret_cast<float4*>(out)[i] = v;
    }
}

extern "C" void kernel_launch(void* const* d_in, const int* in_sizes, int n_in,
                              void* d_out, int out_size, void* d_ws, size_t ws_size,
                              hipStream_t stream) {
    // Inputs (setup_inputs order): x (bsz*16 f32), theta_rx (1), theta_ry (1), theta_rz (1).
    const float* theta_rx = (const float*)d_in[1];
    const float* theta_ry = (const float*)d_in[2];
    float* out = (float*)d_out;

    int n4 = out_size / 4;      // float4 chunks (out_size = 2^21 floats)
    int block = 256;
    int grid = (n4 + block - 1) / block;  // 2048 blocks
    pqc_broadcast_kernel<<<grid, block, 0, stream>>>(theta_rx, theta_ry, out, n4);
}